// Round 3
// baseline (171.883 us; speedup 1.0000x reference)
//
#include <hip/hip_runtime.h>
#include <math.h>

// Problem constants (from reference)
#define Gc 36
#define Ac 5
#define Bc 32
#define Tc 8
#define NCELLS (Bc*Gc*Gc*Ac)     // 207360
#define NFLOATS (NCELLS*5)       // 1036800
#define NF4 (NFLOATS/4)          // 259200
#define NT 256
#define CONF_BLOCKS 128
#define GRID (CONF_BLOCKS + 256) // 384

// ws layout (floats / ints):
//   ws_f[0..127]          conf^2 partials (CONF_BLOCKS)
//   ws_i[256..511]        lin per target
//   ws_i[512..767]        winner flag per target
//   ws_f[1024..1279]      landmark dist per target (0 for non-winner)
//   ws_i[2048]            completion counter C (starts at poison P)
//   ws_i[2060]            mirror M, never written (stays at poison P).
//                         48-byte separation -> identical under any fill
//                         pattern whose period divides 48.

__device__ __forceinline__ void target_meta(const float* __restrict__ bbox_tgt,
                                            int tgt, bool& valid, int& gi, int& gj,
                                            float& fx, float& fy, float& w, float& h,
                                            int& best_a) {
    const float* tg = bbox_tgt + (size_t)tgt * 4;
    float x = tg[0], y = tg[1];
    w = tg[2]; h = tg[3];
    valid = ((x + y + w + h) != 0.0f);
    float gx = x * (float)Gc, gy = y * (float)Gc;
    gi = (int)floorf(gx); gj = (int)floorf(gy);
    fx = gx - floorf(gx); fy = gy - floorf(gy);

    // anchor IoU argmax (first-max tie-break via strict >)
    float x1a = fx - w * 0.5f, x2a = fx + w * 0.5f;
    float y1a = fy - h * 0.5f, y2a = fy + h * 0.5f;
    float a1 = (x2a - x1a + 1.0f) * (y2a - y1a + 1.0f);
    const float adim[Ac] = {0.24f, 0.12f, 0.08f, 0.28f, 0.15f};
    best_a = 0;
    float best_iou = -1e30f;
    for (int a = 0; a < Ac; ++a) {
        float x1b = 0.5f - adim[a] * 0.5f, x2b = 0.5f + adim[a] * 0.5f;
        float iw = fminf(x2a, x2b) - fmaxf(x1a, x1b) + 1.0f;
        float ih = fminf(y2a, x2b) - fmaxf(y1a, x1b) + 1.0f;  // square anchors
        float inter = iw * ih;
        float a2 = (x2b - x1b + 1.0f) * (x2b - x1b + 1.0f);
        float iou = inter / (a1 + a2 - inter + 1e-16f);
        if (iou > best_iou) { best_iou = iou; best_a = a; }
    }
}

// ---------------------------------------------------------------------------
// Conf partials (identical math to verified R0 do_conf)
// ---------------------------------------------------------------------------
__device__ __forceinline__ void do_conf(const float* __restrict__ bbox_pred,
                                        float* __restrict__ ws_f) {
    __shared__ float red[NT];
    const float4* p4 = (const float4*)bbox_pred;
    float acc = 0.0f;
    for (int j = blockIdx.x * NT + threadIdx.x; j < NF4;
         j += CONF_BLOCKS * NT) {
        float4 f = p4[j];
        int r = (4 * j) % 5;   // position of f.x within its 5-group
        float v = (r == 4) ? f.x : (r == 3) ? f.y : (r == 2) ? f.z
                : (r == 1) ? f.w : 0.0f;
        acc += v * v;
    }
    red[threadIdx.x] = acc;
    __syncthreads();
    for (int s = NT / 2; s > 0; s >>= 1) {
        if (threadIdx.x < s) red[threadIdx.x] += red[threadIdx.x + s];
        __syncthreads();
    }
    if (threadIdx.x == 0) ws_f[blockIdx.x] = red[0];
}

// ---------------------------------------------------------------------------
// Per-target block: meta + winner + landmark dist  (identical math to R0)
// PLUS best_pred output row (moved here from do_final — no cross-block dep,
// so it runs in phase 1 instead of the serialized tail).
// ---------------------------------------------------------------------------
__device__ __forceinline__ void do_target(const float* __restrict__ bbox_pred,
                                          const float* __restrict__ lm_pred,
                                          const float* __restrict__ bbox_tgt,
                                          const float* __restrict__ lm_tgt,
                                          float* __restrict__ ws_f,
                                          int* __restrict__ ws_i,
                                          float* __restrict__ out) {
    const int tgt = blockIdx.x - CONF_BLOCKS;   // 0..255
    const int b = tgt >> 3, t = tgt & 7;
    const int tid = threadIdx.x;
    __shared__ int s_lin8[8];

    if (tid < 8) {   // lanes 0..7: lin for this batch's 8 targets
        bool v; int gi, gj, ba; float fx, fy, w, h;
        target_meta(bbox_tgt, (b << 3) + tid, v, gi, gj, fx, fy, w, h, ba);
        s_lin8[tid] = v ? (((b * Gc + gj) * Gc + gi) * Ac + ba) : NCELLS;
    }
    __syncthreads();

    if (tid < 64) {
        int lin = s_lin8[t];
        bool valid = (lin != NCELLS);
        bool winner = valid;
        if (valid)
            for (int t2 = t + 1; t2 < Tc; ++t2)
                if (s_lin8[t2] == lin) { winner = false; break; }

        float acc = 0.0f;
        if (winner && tid < 34) {
            const float4* lp = (const float4*)(lm_pred + (size_t)lin * 136);
            const float4* lt = (const float4*)(lm_tgt + (size_t)tgt * 136);
            float4 a = lp[tid], c = lt[tid];
            float dx = a.x - c.x, dy = a.y - c.y;
            float dz = a.z - c.z, dw = a.w - c.w;
            acc = dx * dx + dy * dy + dz * dz + dw * dw;
        }
        for (int off = 32; off > 0; off >>= 1)
            acc += __shfl_down(acc, off, 64);

        if (tid == 0) {
            ws_i[256 + tgt] = lin;
            ws_i[512 + tgt] = winner ? 1 : 0;
            ws_f[1024 + tgt] = winner ? sqrtf(acc) : 0.0f;
        }
    }

    // best_pred row for this target (thread 0; identical expressions to the
    // R0 do_final version, just relocated)
    if (tid == 0) {
        bool valid; int gi, gj, best_a; float fx, fy, w, h;
        target_meta(bbox_tgt, tgt, valid, gi, gj, fx, fy, w, h, best_a);
        float l0 = log1pf(fx), l1 = log1pf(fy), l2 = log1pf(w), l3 = log1pf(h);

        const float* cp = bbox_pred + (size_t)((b * Gc + gj) * Gc + gi) * Ac * 5;
        float x1g = l0 - l2 * 0.5f, x2g = l0 + l2 * 0.5f;
        float y1g = l1 - l3 * 0.5f, y2g = l1 + l3 * 0.5f;
        float ag = (x2g - x1g + 1.0f) * (y2g - y1g + 1.0f);
        int bp_idx = 0;
        float bp_iou = -1e30f;
        for (int a = 0; a < Ac; ++a) {
            float cx = cp[a * 5 + 0], cy = cp[a * 5 + 1];
            float pw = cp[a * 5 + 2], ph = cp[a * 5 + 3];
            float x1p = cx - pw * 0.5f, x2p = cx + pw * 0.5f;
            float y1p = cy - ph * 0.5f, y2p = cy + ph * 0.5f;
            float iw = fminf(x2g, x2p) - fmaxf(x1g, x1p) + 1.0f;
            float ih = fminf(y2g, y2p) - fmaxf(y1g, y1p) + 1.0f;
            float inter = iw * ih;
            float ap = (x2p - x1p + 1.0f) * (y2p - y1p + 1.0f);
            float iou = inter / (ag + ap - inter + 1e-16f);
            if (iou > bp_iou) { bp_iou = iou; bp_idx = a; }
        }
        float bx = cp[bp_idx * 5 + 0], by = cp[bp_idx * 5 + 1];
        float bw = cp[bp_idx * 5 + 2], bh = cp[bp_idx * 5 + 3];
        float bconf = cp[bp_idx * 5 + 4];
        float* op = out + 3 + (size_t)tgt * 5;
        if (valid) {
            op[0] = bx - bw * 0.5f; op[1] = bx + bw * 0.5f;
            op[2] = by - bh * 0.5f; op[3] = by + bh * 0.5f; op[4] = bconf;
        } else {
            op[0] = 0.0f; op[1] = 0.0f; op[2] = 0.0f; op[3] = 0.0f; op[4] = 0.0f;
        }
    }
}

// ---------------------------------------------------------------------------
// Final combine tail: ONLY the three scalar sums now (best_pred moved out).
// Packed single barrier tree — per-component pairwise order identical to the
// verified R0 block_sums -> bit-exact.
// ---------------------------------------------------------------------------
__device__ __forceinline__ void do_final(const float* __restrict__ bbox_pred,
                                         const float* __restrict__ bbox_tgt,
                                         const float* __restrict__ ws_f,
                                         const int* __restrict__ ws_i,
                                         float* __restrict__ out) {
    const int tid = threadIdx.x;
    __shared__ float4 s_red4[NT];
    __shared__ float  s_reds[NT];
    __shared__ int    s_cnt[NT];

    bool valid; int gi, gj, best_a; float fx, fy, w, h;
    target_meta(bbox_tgt, tid, valid, gi, gj, fx, fy, w, h, best_a);
    int lin = ws_i[256 + tid];
    int winner = ws_i[512 + tid];
    float dist = ws_f[1024 + tid];

    float l0 = log1pf(fx), l1 = log1pf(fy), l2 = log1pf(w), l3 = log1pf(h);
    (void)l0; (void)l1;

    float c_nme = 0.0f, c_sl1 = 0.0f, c_cobj = 0.0f, c_csq = 0.0f;
    if (winner) {
        const float* bp = bbox_pred + (size_t)lin * 5;
        float conf = bp[4];
        c_cobj = (conf - 1.0f) * (conf - 1.0f);
        c_csq = conf * conf;
        float lb[4] = {l0, l1, l2, l3};
        for (int k = 0; k < 4; ++k) {
            float d = bp[k] - lb[k];
            float ad = fabsf(d);
            c_sl1 += (ad < 1.0f) ? 0.5f * d * d : (ad - 0.5f);
        }
        c_nme = dist / (sqrtf(l2 * l3) * 288.0f * 68.0f);
    }

    s_cnt[tid] = winner;
    s_red4[tid] = make_float4(c_nme, c_sl1, c_cobj, c_csq);
    s_reds[tid] = (tid < CONF_BLOCKS) ? ws_f[tid] : 0.0f;
    __syncthreads();
    for (int s = NT / 2; s > 0; s >>= 1) {
        if (tid < s) {
            s_cnt[tid] += s_cnt[tid + s];
            float4 a = s_red4[tid], c = s_red4[tid + s];
            a.x += c.x; a.y += c.y; a.z += c.z; a.w += c.w;
            s_red4[tid] = a;
            s_reds[tid] += s_reds[tid + s];
        }
        __syncthreads();
    }

    if (tid == 0) {
        int cnt = s_cnt[0];
        float nobj = fmaxf((float)cnt, 1.0f);
        float n_noobj = fmaxf((float)(NCELLS - cnt), 1.0f);
        float4 sums = s_red4[0];
        float s_total = s_reds[0];
        out[0] = sums.x / nobj;
        out[1] = 5.0f * sums.y / (nobj * 4.0f);
        out[2] = 0.5f * (s_total - sums.w) / n_noobj + sums.z / nobj;
    }
}

// ---------------------------------------------------------------------------
// Single fused kernel, single dispatch, NO host-side counter reset:
// the completion counter starts at the (unknown, uniform) ws poison value P;
// a never-written mirror word 48 B away also holds P. Last-done detection is
// (old - P) % GRID == GRID-1 — u32 modular arithmetic, wrap-safe, and robust
// even if ws is NOT re-poisoned between launches (C then accumulates exactly
// GRID per launch, which the %GRID absorbs). No block ever waits -> no
// deadlock regardless of scheduling; device-scope atomics + fences handle
// cross-XCD visibility.
// ---------------------------------------------------------------------------
__global__ __launch_bounds__(NT) void k_all(
        const float* __restrict__ bbox_pred,
        const float* __restrict__ lm_pred,
        const float* __restrict__ bbox_tgt,
        const float* __restrict__ lm_tgt,
        float* ws_f, int* ws_i,
        float* __restrict__ out) {
    if (blockIdx.x < CONF_BLOCKS) {
        do_conf(bbox_pred, ws_f);
    } else {
        do_target(bbox_pred, lm_pred, bbox_tgt, lm_tgt, ws_f, ws_i, out);
    }

    // All global ws writes above were performed by threadIdx.x == 0 of each
    // block, so thread 0's release fence covers them.
    __shared__ int s_last;
    if (threadIdx.x == 0) {
        unsigned int P = __hip_atomic_load((unsigned int*)(ws_i + 2060),
                                           __ATOMIC_RELAXED,
                                           __HIP_MEMORY_SCOPE_AGENT);
        __threadfence();                               // release
        unsigned int old = atomicAdd((unsigned int*)(ws_i + 2048), 1u);
        int last = (((old - P) % (unsigned int)GRID) ==
                    (unsigned int)(GRID - 1));
        if (last) __threadfence();                     // acquire
        s_last = last;
    }
    __syncthreads();

    if (s_last) {
        do_final(bbox_pred, bbox_tgt, ws_f, ws_i, out);
    }
}

extern "C" void kernel_launch(void* const* d_in, const int* in_sizes, int n_in,
                              void* d_out, int out_size, void* d_ws, size_t ws_size,
                              hipStream_t stream) {
    const float* bbox_pred = (const float*)d_in[0];
    const float* lm_pred   = (const float*)d_in[1];
    const float* bbox_tgt  = (const float*)d_in[2];
    const float* lm_tgt    = (const float*)d_in[3];
    float* out = (float*)d_out;
    float* ws_f = (float*)d_ws;
    int* ws_i = (int*)d_ws;

    k_all<<<GRID, NT, 0, stream>>>(bbox_pred, lm_pred, bbox_tgt, lm_tgt,
                                   ws_f, ws_i, out);
}

// Round 4
// 152.417 us; speedup vs baseline: 1.1277x; 1.1277x over previous
//
#include <hip/hip_runtime.h>
#include <math.h>

// Problem constants (from reference)
#define Gc 36
#define Ac 5
#define Bc 32
#define Tc 8
#define NCELLS (Bc*Gc*Gc*Ac)     // 207360
#define NFLOATS (NCELLS*5)       // 1036800
#define NF4 (NFLOATS/4)          // 259200
#define NT 256
#define CONF_BLOCKS 128

// ws layout (floats / ints):
//   ws_f[0..127]          conf^2 partials (CONF_BLOCKS)
//   ws_i[256..511]        lin per target
//   ws_i[512..767]        winner flag per target
//   ws_f[1024..1279]      landmark dist per target (0 for non-winner)

__device__ __forceinline__ void target_meta(const float* __restrict__ bbox_tgt,
                                            int tgt, bool& valid, int& gi, int& gj,
                                            float& fx, float& fy, float& w, float& h,
                                            int& best_a) {
    const float* tg = bbox_tgt + (size_t)tgt * 4;
    float x = tg[0], y = tg[1];
    w = tg[2]; h = tg[3];
    valid = ((x + y + w + h) != 0.0f);
    float gx = x * (float)Gc, gy = y * (float)Gc;
    gi = (int)floorf(gx); gj = (int)floorf(gy);
    fx = gx - floorf(gx); fy = gy - floorf(gy);

    // anchor IoU argmax (first-max tie-break via strict >)
    float x1a = fx - w * 0.5f, x2a = fx + w * 0.5f;
    float y1a = fy - h * 0.5f, y2a = fy + h * 0.5f;
    float a1 = (x2a - x1a + 1.0f) * (y2a - y1a + 1.0f);
    const float adim[Ac] = {0.24f, 0.12f, 0.08f, 0.28f, 0.15f};
    best_a = 0;
    float best_iou = -1e30f;
    for (int a = 0; a < Ac; ++a) {
        float x1b = 0.5f - adim[a] * 0.5f, x2b = 0.5f + adim[a] * 0.5f;
        float iw = fminf(x2a, x2b) - fmaxf(x1a, x1b) + 1.0f;
        float ih = fminf(y2a, x2b) - fmaxf(y1a, x1b) + 1.0f;  // square anchors
        float inter = iw * ih;
        float a2 = (x2b - x1b + 1.0f) * (x2b - x1b + 1.0f);
        float iou = inter / (a1 + a2 - inter + 1e-16f);
        if (iou > best_iou) { best_iou = iou; best_a = a; }
    }
}

// ---------------------------------------------------------------------------
// K12: blocks 0..127  -> conf^2 partials (float4, coalesced).
//      blocks 128..383 -> per-target meta + landmark dist + best_pred row.
//      No inter-block dependency -> both halves run concurrently.
//      (best_pred relocated here from k3: it has no cross-block dependency,
//       so it runs in the parallel phase instead of the serialized tail.)
// ---------------------------------------------------------------------------
__global__ __launch_bounds__(NT) void k12_conf_lm(
        const float* __restrict__ bbox_pred,
        const float* __restrict__ lm_pred,
        const float* __restrict__ bbox_tgt,
        const float* __restrict__ lm_tgt,
        float* __restrict__ ws_f, int* __restrict__ ws_i,
        float* __restrict__ out) {
    if (blockIdx.x < CONF_BLOCKS) {
        __shared__ float red[NT];
        const float4* p4 = (const float4*)bbox_pred;
        float acc = 0.0f;
        for (int j = blockIdx.x * NT + threadIdx.x; j < NF4;
             j += CONF_BLOCKS * NT) {
            float4 f = p4[j];
            int r = (4 * j) % 5;   // position of f.x within its 5-group
            float v = (r == 4) ? f.x : (r == 3) ? f.y : (r == 2) ? f.z
                    : (r == 1) ? f.w : 0.0f;
            acc += v * v;
        }
        red[threadIdx.x] = acc;
        __syncthreads();
        for (int s = NT / 2; s > 0; s >>= 1) {
            if (threadIdx.x < s) red[threadIdx.x] += red[threadIdx.x + s];
            __syncthreads();
        }
        if (threadIdx.x == 0) ws_f[blockIdx.x] = red[0];
    } else {
        const int tgt = blockIdx.x - CONF_BLOCKS;   // 0..255
        const int b = tgt >> 3, t = tgt & 7;
        const int tid = threadIdx.x;
        __shared__ int s_lin8[8];

        if (tid < 8) {   // lanes 0..7: lin for this batch's 8 targets
            bool v; int gi, gj, ba; float fx, fy, w, h;
            target_meta(bbox_tgt, (b << 3) + tid, v, gi, gj, fx, fy, w, h, ba);
            s_lin8[tid] = v ? (((b * Gc + gj) * Gc + gi) * Ac + ba) : NCELLS;
        }
        __syncthreads();

        if (tid < 64) {
            int lin = s_lin8[t];
            bool valid = (lin != NCELLS);
            bool winner = valid;
            if (valid)
                for (int t2 = t + 1; t2 < Tc; ++t2)
                    if (s_lin8[t2] == lin) { winner = false; break; }

            float acc = 0.0f;
            if (winner && tid < 34) {
                const float4* lp = (const float4*)(lm_pred + (size_t)lin * 136);
                const float4* lt = (const float4*)(lm_tgt + (size_t)tgt * 136);
                float4 a = lp[tid], c = lt[tid];
                float dx = a.x - c.x, dy = a.y - c.y;
                float dz = a.z - c.z, dw = a.w - c.w;
                acc = dx * dx + dy * dy + dz * dz + dw * dw;
            }
            for (int off = 32; off > 0; off >>= 1)
                acc += __shfl_down(acc, off, 64);

            if (tid == 0) {
                ws_i[256 + tgt] = lin;
                ws_i[512 + tgt] = winner ? 1 : 0;
                ws_f[1024 + tgt] = winner ? sqrtf(acc) : 0.0f;
            }
        }

        // best_pred row for this target (thread 0; expressions identical to
        // the verified R0 k3 version, just relocated — confirmed bit-exact
        // in the R3 passing run)
        if (tid == 0) {
            bool valid; int gi, gj, best_a; float fx, fy, w, h;
            target_meta(bbox_tgt, tgt, valid, gi, gj, fx, fy, w, h, best_a);
            float l0 = log1pf(fx), l1 = log1pf(fy);
            float l2 = log1pf(w),  l3 = log1pf(h);

            const float* cp = bbox_pred
                            + (size_t)((b * Gc + gj) * Gc + gi) * Ac * 5;
            float x1g = l0 - l2 * 0.5f, x2g = l0 + l2 * 0.5f;
            float y1g = l1 - l3 * 0.5f, y2g = l1 + l3 * 0.5f;
            float ag = (x2g - x1g + 1.0f) * (y2g - y1g + 1.0f);
            int bp_idx = 0;
            float bp_iou = -1e30f;
            for (int a = 0; a < Ac; ++a) {
                float cx = cp[a * 5 + 0], cy = cp[a * 5 + 1];
                float pw = cp[a * 5 + 2], ph = cp[a * 5 + 3];
                float x1p = cx - pw * 0.5f, x2p = cx + pw * 0.5f;
                float y1p = cy - ph * 0.5f, y2p = cy + ph * 0.5f;
                float iw = fminf(x2g, x2p) - fmaxf(x1g, x1p) + 1.0f;
                float ih = fminf(y2g, y2p) - fmaxf(y1g, y1p) + 1.0f;
                float inter = iw * ih;
                float ap = (x2p - x1p + 1.0f) * (y2p - y1p + 1.0f);
                float iou = inter / (ag + ap - inter + 1e-16f);
                if (iou > bp_iou) { bp_iou = iou; bp_idx = a; }
            }
            float bx = cp[bp_idx * 5 + 0], by = cp[bp_idx * 5 + 1];
            float bw = cp[bp_idx * 5 + 2], bh = cp[bp_idx * 5 + 3];
            float bconf = cp[bp_idx * 5 + 4];
            float* op = out + 3 + (size_t)tgt * 5;
            if (valid) {
                op[0] = bx - bw * 0.5f; op[1] = bx + bw * 0.5f;
                op[2] = by - bh * 0.5f; op[3] = by + bh * 0.5f; op[4] = bconf;
            } else {
                op[0] = 0.0f; op[1] = 0.0f; op[2] = 0.0f;
                op[3] = 0.0f; op[4] = 0.0f;
            }
        }
    }
}

// ---------------------------------------------------------------------------
// K3: final combine (1 block, 256 threads = one thread per target).
// Scalar sums only (best_pred moved to k12). Packed single barrier tree —
// per-component pairwise order identical to R0's separate block_sums
// (verified bit-exact in R2/R3 passing runs).
// ---------------------------------------------------------------------------
__global__ __launch_bounds__(NT) void k3_final(
        const float* __restrict__ bbox_pred,
        const float* __restrict__ bbox_tgt,
        const float* __restrict__ ws_f,
        const int* __restrict__ ws_i,
        float* __restrict__ out) {
    const int tid = threadIdx.x;
    __shared__ float4 s_red4[NT];
    __shared__ float  s_reds[NT];
    __shared__ int    s_cnt[NT];

    bool valid; int gi, gj, best_a; float fx, fy, w, h;
    target_meta(bbox_tgt, tid, valid, gi, gj, fx, fy, w, h, best_a);
    int lin = ws_i[256 + tid];
    int winner = ws_i[512 + tid];
    float dist = ws_f[1024 + tid];

    float l0 = log1pf(fx), l1 = log1pf(fy), l2 = log1pf(w), l3 = log1pf(h);

    float c_nme = 0.0f, c_sl1 = 0.0f, c_cobj = 0.0f, c_csq = 0.0f;
    if (winner) {
        const float* bp = bbox_pred + (size_t)lin * 5;
        float conf = bp[4];
        c_cobj = (conf - 1.0f) * (conf - 1.0f);
        c_csq = conf * conf;
        float lb[4] = {l0, l1, l2, l3};
        for (int k = 0; k < 4; ++k) {
            float d = bp[k] - lb[k];
            float ad = fabsf(d);
            c_sl1 += (ad < 1.0f) ? 0.5f * d * d : (ad - 0.5f);
        }
        c_nme = dist / (sqrtf(l2 * l3) * 288.0f * 68.0f);
    }

    s_cnt[tid] = winner;
    s_red4[tid] = make_float4(c_nme, c_sl1, c_cobj, c_csq);
    s_reds[tid] = (tid < CONF_BLOCKS) ? ws_f[tid] : 0.0f;
    __syncthreads();
    for (int s = NT / 2; s > 0; s >>= 1) {
        if (tid < s) {
            s_cnt[tid] += s_cnt[tid + s];
            float4 a = s_red4[tid], c = s_red4[tid + s];
            a.x += c.x; a.y += c.y; a.z += c.z; a.w += c.w;
            s_red4[tid] = a;
            s_reds[tid] += s_reds[tid + s];
        }
        __syncthreads();
    }

    if (tid == 0) {
        int cnt = s_cnt[0];
        float nobj = fmaxf((float)cnt, 1.0f);
        float n_noobj = fmaxf((float)(NCELLS - cnt), 1.0f);
        float4 sums = s_red4[0];
        float s_total = s_reds[0];
        out[0] = sums.x / nobj;
        out[1] = 5.0f * sums.y / (nobj * 4.0f);
        out[2] = 0.5f * (s_total - sums.w) / n_noobj + sums.z / nobj;
    }
}

extern "C" void kernel_launch(void* const* d_in, const int* in_sizes, int n_in,
                              void* d_out, int out_size, void* d_ws, size_t ws_size,
                              hipStream_t stream) {
    const float* bbox_pred = (const float*)d_in[0];
    const float* lm_pred   = (const float*)d_in[1];
    const float* bbox_tgt  = (const float*)d_in[2];
    const float* lm_tgt    = (const float*)d_in[3];
    float* out = (float*)d_out;
    float* ws_f = (float*)d_ws;
    int* ws_i = (int*)d_ws;

    k12_conf_lm<<<CONF_BLOCKS + 256, NT, 0, stream>>>(bbox_pred, lm_pred,
                                                      bbox_tgt, lm_tgt,
                                                      ws_f, ws_i, out);
    k3_final<<<1, NT, 0, stream>>>(bbox_pred, bbox_tgt, ws_f, ws_i, out);
}